// Round 1
// baseline (300.806 us; speedup 1.0000x reference)
//
#include <hip/hip_runtime.h>

// Problem constants (from reference setup_inputs):
//   kernel: (8, 25, 508, 508) f32   tensor: (8, 3, 512, 512) f32
//   crop logic is a no-op at these sizes (needed == h == 512).
// weighted[b,c,y,x] = sum_{di,dj} kernel[b, di*5+dj, y, x] * tensor[b, c, y+di, x+dj]
// kernel_sum[b,0,y,x] = sum_k kernel[b,k,y,x]
// Output = weighted (6,193,536) ++ kernel_sum (2,064,512), f32.

constexpr int BS = 8;
constexpr int CI = 3;
constexpr int KH = 508;
constexpr int KW = 508;
constexpr int TH = 512;
constexpr int TW = 512;
constexpr int KSZ = 5;
constexpr int KK = KSZ * KSZ;
constexpr int QPR = KW / 4;                       // 127 float4-quads per row
constexpr long long KPLANE = (long long)KH * KW;  // 258064
constexpr long long WOUT_SIZE = (long long)BS * CI * KPLANE;  // 6193536

__global__ __launch_bounds__(256) void apply_kernels_kern(
    const float* __restrict__ kern,
    const float* __restrict__ tens,
    float* __restrict__ out)
{
    int tid = blockIdx.x * 256 + threadIdx.x;
    if (tid >= BS * KH * QPR) return;
    int q = tid % QPR;
    int t = tid / QPR;
    int y = t % KH;
    int b = t / KH;
    int x = q * 4;

    // Thread covers output pixels (y, x..x+3) for all 3 channels + kernel_sum.
    const float* kbase = kern + (size_t)b * KK * KPLANE + (size_t)y * KW + x;
    const float* tbase = tens + (size_t)b * CI * TH * TW + (size_t)y * TW + x;

    float acc[CI][4] = {};
    float ksum[4] = {};

#pragma unroll
    for (int di = 0; di < KSZ; ++di) {
        // 8-float tensor window per channel for row y+di: covers x .. x+7
        float tr[CI][8];
#pragma unroll
        for (int c = 0; c < CI; ++c) {
            const float* tp = tbase + (size_t)c * TH * TW + (size_t)di * TW;
            const float4 a  = *(const float4*)(tp);
            const float4 b4 = *(const float4*)(tp + 4);
            tr[c][0] = a.x;  tr[c][1] = a.y;  tr[c][2] = a.z;  tr[c][3] = a.w;
            tr[c][4] = b4.x; tr[c][5] = b4.y; tr[c][6] = b4.z; tr[c][7] = b4.w;
        }
#pragma unroll
        for (int dj = 0; dj < KSZ; ++dj) {
            // coalesced 16B/lane kernel load; each kernel element read exactly once
            const float4 k4 = *(const float4*)(kbase + (size_t)(di * KSZ + dj) * KPLANE);
            const float kv[4] = {k4.x, k4.y, k4.z, k4.w};
#pragma unroll
            for (int l = 0; l < 4; ++l) {
                ksum[l] += kv[l];
#pragma unroll
                for (int c = 0; c < CI; ++c)
                    acc[c][l] += kv[l] * tr[c][l + dj];  // output pixel x+l taps tensor x+l+dj
            }
        }
    }

#pragma unroll
    for (int c = 0; c < CI; ++c) {
        float4 v = {acc[c][0], acc[c][1], acc[c][2], acc[c][3]};
        *(float4*)(out + ((size_t)(b * CI + c) * KH + y) * KW + x) = v;
    }
    float4 s = {ksum[0], ksum[1], ksum[2], ksum[3]};
    *(float4*)(out + WOUT_SIZE + ((size_t)b * KH + y) * KW + x) = s;
}

extern "C" void kernel_launch(void* const* d_in, const int* in_sizes, int n_in,
                              void* d_out, int out_size, void* d_ws, size_t ws_size,
                              hipStream_t stream) {
    const float* kern = (const float*)d_in[0];
    const float* tens = (const float*)d_in[1];
    float* out = (float*)d_out;
    const int total = BS * KH * QPR;
    const int blocks = (total + 255) / 256;
    apply_kernels_kern<<<blocks, 256, 0, stream>>>(kern, tens, out);
}

// Round 3
// 297.892 us; speedup vs baseline: 1.0098x; 1.0098x over previous
//
#include <hip/hip_runtime.h>

// kernel: (8, 25, 508, 508) f32   tensor: (8, 3, 512, 512) f32
// weighted[b,c,y,x] = sum_{di,dj} kernel[b, di*5+dj, y, x] * tensor[b, c, y+di, x+dj]
// kernel_sum[b,0,y,x] = sum_k kernel[b,k,y,x]
// Output = weighted (6,193,536) ++ kernel_sum (2,064,512), f32.
//
// R2: same as R1 but nontemporal builtins use a native Clang vector type
// (HIP float4 is a struct; the builtin requires vector-of-scalar).

constexpr int BS = 8;
constexpr int CI = 3;
constexpr int KH = 508;
constexpr int KW = 508;
constexpr int TH = 512;
constexpr int TW = 512;
constexpr int KSZ = 5;
constexpr int KK = KSZ * KSZ;
constexpr int QPR = KW / 4;            // 127 quads per row
constexpr int YPAIRS = KH / 2;         // 254
constexpr long long KPLANE = (long long)KH * KW;             // 258064
constexpr long long WOUT_SIZE = (long long)BS * CI * KPLANE; // 6193536

typedef float vf4 __attribute__((ext_vector_type(4)));

__device__ __forceinline__ vf4 nt_load4(const float* p) {
    return __builtin_nontemporal_load((const vf4*)p);
}
__device__ __forceinline__ void nt_store4(float* p, vf4 v) {
    __builtin_nontemporal_store(v, (vf4*)p);
}

__global__ __launch_bounds__(256) void apply_kernels_kern(
    const float* __restrict__ kern,
    const float* __restrict__ tens,
    float* __restrict__ out)
{
    int tid = blockIdx.x * 256 + threadIdx.x;
    if (tid >= BS * YPAIRS * QPR) return;
    int q = tid % QPR;
    int t = tid / QPR;
    int yi = t % YPAIRS;
    int b = t / YPAIRS;
    int y0 = yi * 2;               // this thread does output rows y0, y0+1
    int x = q * 4;

    const float* kbase = kern + (size_t)b * KK * KPLANE + (size_t)y0 * KW + x;
    const float* tbase = tens + (size_t)b * CI * TH * TW + (size_t)y0 * TW + x;

    float acc[2][CI][4] = {};
    float ksum[2][4] = {};

    // Tensor rows y0 .. y0+5 each serve output row y0 (tap di=r) and
    // y0+1 (tap di=r-1).
#pragma unroll
    for (int r = 0; r < KSZ + 1; ++r) {
        float tw[CI][8];
#pragma unroll
        for (int c = 0; c < CI; ++c) {
            const float* tp = tbase + (size_t)c * TH * TW + (size_t)r * TW;
            const vf4 a  = *(const vf4*)(tp);
            const vf4 b4 = *(const vf4*)(tp + 4);
            tw[c][0] = a.x;  tw[c][1] = a.y;  tw[c][2] = a.z;  tw[c][3] = a.w;
            tw[c][4] = b4.x; tw[c][5] = b4.y; tw[c][6] = b4.z; tw[c][7] = b4.w;
        }
#pragma unroll
        for (int o = 0; o < 2; ++o) {
            int di = r - o;
            if (di < 0 || di >= KSZ) continue;
#pragma unroll
            for (int dj = 0; dj < KSZ; ++dj) {
                // read-once kernel tap: nontemporal, coalesced 16B/lane
                const vf4 k4 = nt_load4(kbase + (size_t)o * KW +
                                        (size_t)(di * KSZ + dj) * KPLANE);
                const float kv[4] = {k4.x, k4.y, k4.z, k4.w};
#pragma unroll
                for (int l = 0; l < 4; ++l) {
                    ksum[o][l] += kv[l];
#pragma unroll
                    for (int c = 0; c < CI; ++c)
                        acc[o][c][l] += kv[l] * tw[c][l + dj];
                }
            }
        }
    }

#pragma unroll
    for (int o = 0; o < 2; ++o) {
#pragma unroll
        for (int c = 0; c < CI; ++c) {
            vf4 v = {acc[o][c][0], acc[o][c][1], acc[o][c][2], acc[o][c][3]};
            nt_store4(out + ((size_t)(b * CI + c) * KH + (y0 + o)) * KW + x, v);
        }
        vf4 s = {ksum[o][0], ksum[o][1], ksum[o][2], ksum[o][3]};
        nt_store4(out + WOUT_SIZE + ((size_t)b * KH + (y0 + o)) * KW + x, s);
    }
}

extern "C" void kernel_launch(void* const* d_in, const int* in_sizes, int n_in,
                              void* d_out, int out_size, void* d_ws, size_t ws_size,
                              hipStream_t stream) {
    const float* kern = (const float*)d_in[0];
    const float* tens = (const float*)d_in[1];
    float* out = (float*)d_out;
    const int total = BS * YPAIRS * QPR;
    const int blocks = (total + 255) / 256;
    apply_kernels_kern<<<blocks, 256, 0, stream>>>(kern, tens, out);
}